// Round 4
// baseline (297.402 us; speedup 1.0000x reference)
//
#include <hip/hip_runtime.h>

typedef unsigned short u16t;
typedef unsigned int   u32t;
typedef __bf16 bf16x8 __attribute__((ext_vector_type(8)));
typedef float  f32x4  __attribute__((ext_vector_type(4)));

#define NB   64
#define DIN  1024
#define DOUT 256
#define EPS  1e-4f   // LR*LR
#define KP   68      // LDS row stride in u16: 34 dwords == 2 mod 32 -> conflict-free patterns

#define OUT_STATE (NB*DIN*DOUT)
#define OUT_LL    (OUT_STATE + 1)
#define OUT_RR    (OUT_LL + NB*DIN)

__device__ __forceinline__ u16t f2b(float x) {
    u32t u = __builtin_bit_cast(u32t, x);
    u += 0x7FFFu + ((u >> 16) & 1u);          // RTNE
    return (u16t)(u >> 16);
}
__device__ __forceinline__ float b2f(u16t h) {
    return __builtin_bit_cast(float, ((u32t)h) << 16);
}
// 16B fragment from 8B-aligned LDS (two ds_read_b64)
__device__ __forceinline__ bf16x8 ld_frag(const u16t* p) {
    uint2 lo = *(const uint2*)(p);
    uint2 hi = *(const uint2*)(p + 4);
    union { uint4 u; bf16x8 v; } x;
    x.u = make_uint4(lo.x, lo.y, hi.x, hi.y);
    return x.v;
}
__device__ __forceinline__ void st8(u16t* p, u32t a, u32t b) {
    *(uint2*)(p) = make_uint2(a, b);
}

// ============================================================
// K1: grad row moments -> ll (out), GH = bf16(a*grad), col partials CP.
// No LDS. grid 1024 = (n, 16 i-chunks), block 256. XCD: bid&7 = n&7.
// ============================================================
__global__ __launch_bounds__(256) void k_prep(
    const float* __restrict__ grad, const float* __restrict__ L0,
    float* __restrict__ out, u16t* __restrict__ GH, float* __restrict__ CP)
{
    const int bid = blockIdx.x;
    const int n = (bid & 7) | ((bid >> 7) << 3);
    const int chunk = (bid >> 3) & 15;
    const int tid = threadIdx.x, wave = tid >> 6, lane = tid & 63;
    const int ib = chunk * 64;
    const float* gb = grad + ((size_t)n << 18);
    u16t* GHn = GH + ((size_t)n << 18);

    float4 cacc = {0.f, 0.f, 0.f, 0.f};
    #pragma unroll 4
    for (int r = 0; r < 16; ++r) {
        const int i = ib + wave * 16 + r;
        const float4 v = *(const float4*)(gb + (size_t)i * 256 + lane * 4);
        float s = v.x*v.x + v.y*v.y + v.z*v.z + v.w*v.w;
        cacc.x += v.x*v.x; cacc.y += v.y*v.y; cacc.z += v.z*v.z; cacc.w += v.w*v.w;
        #pragma unroll
        for (int off = 32; off; off >>= 1) s += __shfl_xor(s, off);
        const float l0 = L0[n * DIN + i];
        const float ll = fmaxf(l0, 0.5f * l0 + s * (0.5f / DOUT));
        const float a  = rsqrtf(sqrtf(ll));
        ushort4 g4 = { f2b(v.x*a), f2b(v.y*a), f2b(v.z*a), f2b(v.w*a) };
        *(ushort4*)(GHn + (size_t)i * 256 + lane * 4) = g4;
        if (lane == 0) out[OUT_LL + n * DIN + i] = ll;
    }
    const int slot = chunk * 4 + wave;
    *(float4*)(CP + ((size_t)(n * 64 + slot)) * 256 + lane * 4) = cacc;
}

// ============================================================
// K2: reduce col partials -> rr (out), BS = rr^-1/4 ; copy state
// ============================================================
__global__ __launch_bounds__(256) void k_cols(
    const float* __restrict__ R0, const float* __restrict__ state,
    float* __restrict__ out, float* __restrict__ BS, const float* __restrict__ CP)
{
    const int n = blockIdx.x, o = threadIdx.x;
    const float* cp = CP + (size_t)n * 64 * 256 + o;
    float s = 0.f;
    #pragma unroll 8
    for (int k = 0; k < 64; ++k) s += cp[k * 256];
    const float r0 = R0[n * DOUT + o];
    const float rr = fmaxf(r0, 0.5f * r0 + s * (0.5f / DIN));
    out[OUT_RR + n * DOUT + o] = rr;
    BS[n * DOUT + o] = rsqrtf(sqrtf(rr));
    if (n == 0 && o == 0) out[OUT_STATE] = state[0];
}

// ============================================================
// G1 (k_T): TT[o][p] = b[o] * sum_i GH[i][o] * M[i][p]
// tile 128o x 128p, K=1024. grid 256 = (n, 4 tiles). Both operands
// transpose-staged (GH bf16 cols; M fp32 cols cvt on the fly).
// ============================================================
__global__ __launch_bounds__(256, 4) void k_T(
    const u16t* __restrict__ GH, const float* __restrict__ M,
    const float* __restrict__ BS, u16t* __restrict__ TT)
{
    __shared__ u16t sA[128 * KP];   // [o][i]
    __shared__ u16t sB[128 * KP];   // [p][i]
    const int bid = blockIdx.x;
    const int n = (bid & 7) | ((bid >> 5) << 3);
    const int tile = (bid >> 3) & 3;
    const int o0 = (tile & 1) * 128, p0 = (tile >> 1) * 128;
    const int tid = threadIdx.x, lane = tid & 63, w = tid >> 6;
    const int wr = w >> 1, wc = w & 1, t16 = lane & 15, g4 = lane >> 4;
    const u16t* GHn = GH + ((size_t)n << 18);
    const float* Mn = M + ((size_t)n << 18);
    f32x4 acc[4][4] = {};
    for (int ch = 0; ch < 16; ++ch) {
        const int ib = ch * 64;
        __syncthreads();
        // sA: transpose-stage GH rows (o-major). bank = 2*lane -> free
        #pragma unroll
        for (int r = 0; r < 16; ++r) {
            const int il = w * 16 + r;
            const u16t* src = GHn + (size_t)(ib + il) * 256 + o0;
            sA[(size_t)lane * KP + il]        = src[lane];
            sA[(size_t)(lane + 64) * KP + il] = src[lane + 64];
        }
        // sB: transpose-stage fp32 M rows, cvt to bf16
        #pragma unroll
        for (int r = 0; r < 16; ++r) {
            const int il = w * 16 + r;
            const float* src = Mn + (size_t)(ib + il) * 256 + p0;
            sB[(size_t)lane * KP + il]        = f2b(src[lane]);
            sB[(size_t)(lane + 64) * KP + il] = f2b(src[lane + 64]);
        }
        __syncthreads();
        #pragma unroll
        for (int kb = 0; kb < 2; ++kb) {
            const int ko = kb * 32 + g4 * 8;
            bf16x8 fa[4], fb[4];
            #pragma unroll
            for (int fm = 0; fm < 4; ++fm)
                fa[fm] = ld_frag(sA + (wr*64 + fm*16 + t16) * KP + ko);
            #pragma unroll
            for (int fn = 0; fn < 4; ++fn)
                fb[fn] = ld_frag(sB + (wc*64 + fn*16 + t16) * KP + ko);
            #pragma unroll
            for (int fm = 0; fm < 4; ++fm)
                #pragma unroll
                for (int fn = 0; fn < 4; ++fn)
                    acc[fm][fn] = __builtin_amdgcn_mfma_f32_16x16x32_bf16(fa[fm], fb[fn], acc[fm][fn], 0, 0, 0);
        }
    }
    const float* bs = BS + n * DOUT;
    u16t* TTn = TT + ((size_t)n << 16);
    #pragma unroll
    for (int fm = 0; fm < 4; ++fm)
        #pragma unroll
        for (int fn = 0; fn < 4; ++fn) {
            const int p = p0 + wc*64 + fn*16 + t16;
            #pragma unroll
            for (int r = 0; r < 4; ++r) {
                const int o = o0 + wr*64 + fm*16 + g4*4 + r;
                TTn[o * 256 + p] = f2b(acc[fm][fn][r] * bs[o]);
            }
        }
}

// ============================================================
// G2 (k_Abuild): A[i][o] = M + EPS*( sum_p M[i][p]*TT[o][p] - b_o*GH[i][o] )
// tile 128i x 256o (full), K=256. grid 512 = (n, 8 i-tiles). -> AH bf16
// ============================================================
__global__ __launch_bounds__(256, 3) void k_Abuild(
    const float* __restrict__ M, const u16t* __restrict__ GH,
    const float* __restrict__ BS, const u16t* __restrict__ TT,
    u16t* __restrict__ AH)
{
    __shared__ u16t sA[128 * KP];   // [i][p]
    __shared__ u16t sB[256 * KP];   // [o][p]
    const int bid = blockIdx.x;
    const int n = (bid & 7) | ((bid >> 6) << 3);
    const int i0 = ((bid >> 3) & 7) * 128;
    const int tid = threadIdx.x, lane = tid & 63, w = tid >> 6;
    const int wr = w >> 1, wc = w & 1, t16 = lane & 15, g4 = lane >> 4;
    const float* Mn = M + ((size_t)n << 18);
    const u16t* GHn = GH + ((size_t)n << 18);
    const u16t* TTn = TT + ((size_t)n << 16);
    f32x4 acc[4][8] = {};
    for (int ch = 0; ch < 4; ++ch) {
        const int pb = ch * 64;
        __syncthreads();
        // sA: convert fp32 M rows
        #pragma unroll
        for (int q = 0; q < 8; ++q) {
            const int row = (tid >> 4) + 16 * q;
            const int c4  = tid & 15;
            const float4 v = *(const float4*)(Mn + (size_t)(i0 + row) * 256 + pb + c4 * 4);
            ushort4 h = { f2b(v.x), f2b(v.y), f2b(v.z), f2b(v.w) };
            *(ushort4*)(sA + row * KP + c4 * 4) = h;
        }
        // sB: TT rows
        #pragma unroll
        for (int q = 0; q < 8; ++q) {
            const int row = (tid >> 3) + 32 * q;
            const int c8  = (tid & 7) * 8;
            uint4 v = *(const uint4*)(TTn + (size_t)row * 256 + pb + c8);
            st8(sB + row * KP + c8, v.x, v.y);
            st8(sB + row * KP + c8 + 4, v.z, v.w);
        }
        __syncthreads();
        #pragma unroll
        for (int kb = 0; kb < 2; ++kb) {
            const int ko = kb * 32 + g4 * 8;
            bf16x8 fa[4], fb[8];
            #pragma unroll
            for (int fm = 0; fm < 4; ++fm)
                fa[fm] = ld_frag(sA + (wr*64 + fm*16 + t16) * KP + ko);
            #pragma unroll
            for (int fn = 0; fn < 8; ++fn)
                fb[fn] = ld_frag(sB + (wc*128 + fn*16 + t16) * KP + ko);
            #pragma unroll
            for (int fm = 0; fm < 4; ++fm)
                #pragma unroll
                for (int fn = 0; fn < 8; ++fn)
                    acc[fm][fn] = __builtin_amdgcn_mfma_f32_16x16x32_bf16(fa[fm], fb[fn], acc[fm][fn], 0, 0, 0);
        }
    }
    const float* bs = BS + n * DOUT;
    u16t* AHn = AH + ((size_t)n << 18);
    #pragma unroll
    for (int fm = 0; fm < 4; ++fm)
        #pragma unroll
        for (int fn = 0; fn < 8; ++fn) {
            const int o = wc*128 + fn*16 + t16;
            const float bo = bs[o];
            #pragma unroll
            for (int r = 0; r < 4; ++r) {
                const int i = i0 + wr*64 + fm*16 + g4*4 + r;
                const size_t idx = (size_t)i * 256 + o;
                const float Aval = Mn[idx] + EPS * (acc[fm][fn][r] - bo * b2f(GHn[idx]));
                AHn[idx] = f2b(Aval);
            }
        }
}

// ============================================================
// G3 (k_E): EH[p][o] = bf16( 0.5*(A^T A - I) ). tile 128p x 128o, K=1024.
// grid 256 = (n, 4 tiles). Both operands transpose-staged from AH.
// ============================================================
__global__ __launch_bounds__(256, 4) void k_E(
    const u16t* __restrict__ AH, u16t* __restrict__ EH)
{
    __shared__ u16t sA[128 * KP];   // [p][i]
    __shared__ u16t sB[128 * KP];   // [o][i]
    const int bid = blockIdx.x;
    const int n = (bid & 7) | ((bid >> 5) << 3);
    const int tile = (bid >> 3) & 3;
    const int p0 = (tile >> 1) * 128, o0 = (tile & 1) * 128;
    const bool diag = (p0 == o0);
    const int tid = threadIdx.x, lane = tid & 63, w = tid >> 6;
    const int wr = w >> 1, wc = w & 1, t16 = lane & 15, g4 = lane >> 4;
    const u16t* AHn = AH + ((size_t)n << 18);
    f32x4 acc[4][4] = {};
    for (int ch = 0; ch < 16; ++ch) {
        const int ib = ch * 64;
        __syncthreads();
        #pragma unroll
        for (int r = 0; r < 16; ++r) {
            const int il = w * 16 + r;
            const u16t* src = AHn + (size_t)(ib + il) * 256;
            sA[(size_t)lane * KP + il]        = src[p0 + lane];
            sA[(size_t)(lane + 64) * KP + il] = src[p0 + lane + 64];
        }
        if (!diag) {
            #pragma unroll
            for (int r = 0; r < 16; ++r) {
                const int il = w * 16 + r;
                const u16t* src = AHn + (size_t)(ib + il) * 256;
                sB[(size_t)lane * KP + il]        = src[o0 + lane];
                sB[(size_t)(lane + 64) * KP + il] = src[o0 + lane + 64];
            }
        }
        __syncthreads();
        const u16t* sBr = diag ? sA : sB;
        #pragma unroll
        for (int kb = 0; kb < 2; ++kb) {
            const int ko = kb * 32 + g4 * 8;
            bf16x8 fa[4], fb[4];
            #pragma unroll
            for (int fm = 0; fm < 4; ++fm)
                fa[fm] = ld_frag(sA + (wr*64 + fm*16 + t16) * KP + ko);
            #pragma unroll
            for (int fn = 0; fn < 4; ++fn)
                fb[fn] = ld_frag(sBr + (wc*64 + fn*16 + t16) * KP + ko);
            #pragma unroll
            for (int fm = 0; fm < 4; ++fm)
                #pragma unroll
                for (int fn = 0; fn < 4; ++fn)
                    acc[fm][fn] = __builtin_amdgcn_mfma_f32_16x16x32_bf16(fa[fm], fb[fn], acc[fm][fn], 0, 0, 0);
        }
    }
    u16t* EHn = EH + ((size_t)n << 16);
    #pragma unroll
    for (int fm = 0; fm < 4; ++fm)
        #pragma unroll
        for (int fn = 0; fn < 4; ++fn) {
            const int o = o0 + wc*64 + fn*16 + t16;
            #pragma unroll
            for (int r = 0; r < 4; ++r) {
                const int p = p0 + wr*64 + fm*16 + g4*4 + r;
                const float v = 0.5f * acc[fm][fn][r] - (p == o ? 0.5f : 0.f);
                EHn[p * 256 + o] = f2b(v);
            }
        }
}

// ============================================================
// G4 (k_Mnew): Mnew[i][o] = b2f(AH[i][o]) - sum_p AH[i][p]*EH[o][p] (EH sym)
// tile 128i x 256o, K=256. grid 512 = (n, 8 i-tiles).
// ============================================================
__global__ __launch_bounds__(256, 3) void k_Mnew(
    const u16t* __restrict__ AH, const u16t* __restrict__ EH,
    float* __restrict__ out)
{
    __shared__ u16t sA[128 * KP];   // [i][p]
    __shared__ u16t sB[256 * KP];   // [o][p]
    const int bid = blockIdx.x;
    const int n = (bid & 7) | ((bid >> 6) << 3);
    const int i0 = ((bid >> 3) & 7) * 128;
    const int tid = threadIdx.x, lane = tid & 63, w = tid >> 6;
    const int wr = w >> 1, wc = w & 1, t16 = lane & 15, g4 = lane >> 4;
    const u16t* AHn = AH + ((size_t)n << 18);
    const u16t* EHn = EH + ((size_t)n << 16);
    f32x4 acc[4][8] = {};
    for (int ch = 0; ch < 4; ++ch) {
        const int pb = ch * 64;
        __syncthreads();
        #pragma unroll
        for (int q = 0; q < 4; ++q) {
            const int row = (tid >> 3) + 32 * q;
            const int c8  = (tid & 7) * 8;
            uint4 v = *(const uint4*)(AHn + (size_t)(i0 + row) * 256 + pb + c8);
            st8(sA + row * KP + c8, v.x, v.y);
            st8(sA + row * KP + c8 + 4, v.z, v.w);
        }
        #pragma unroll
        for (int q = 0; q < 8; ++q) {
            const int row = (tid >> 3) + 32 * q;
            const int c8  = (tid & 7) * 8;
            uint4 v = *(const uint4*)(EHn + (size_t)row * 256 + pb + c8);
            st8(sB + row * KP + c8, v.x, v.y);
            st8(sB + row * KP + c8 + 4, v.z, v.w);
        }
        __syncthreads();
        #pragma unroll
        for (int kb = 0; kb < 2; ++kb) {
            const int ko = kb * 32 + g4 * 8;
            bf16x8 fa[4], fb[8];
            #pragma unroll
            for (int fm = 0; fm < 4; ++fm)
                fa[fm] = ld_frag(sA + (wr*64 + fm*16 + t16) * KP + ko);
            #pragma unroll
            for (int fn = 0; fn < 8; ++fn)
                fb[fn] = ld_frag(sB + (wc*128 + fn*16 + t16) * KP + ko);
            #pragma unroll
            for (int fm = 0; fm < 4; ++fm)
                #pragma unroll
                for (int fn = 0; fn < 8; ++fn)
                    acc[fm][fn] = __builtin_amdgcn_mfma_f32_16x16x32_bf16(fa[fm], fb[fn], acc[fm][fn], 0, 0, 0);
        }
    }
    float* outn = out + ((size_t)n << 18);
    #pragma unroll
    for (int fm = 0; fm < 4; ++fm)
        #pragma unroll
        for (int fn = 0; fn < 8; ++fn) {
            const int o = wc*128 + fn*16 + t16;
            #pragma unroll
            for (int r = 0; r < 4; ++r) {
                const int i = i0 + wr*64 + fm*16 + g4*4 + r;
                const size_t idx = (size_t)i * 256 + o;
                outn[idx] = b2f(AHn[idx]) - acc[fm][fn][r];
            }
        }
}

extern "C" void kernel_launch(void* const* d_in, const int* in_sizes, int n_in,
                              void* d_out, int out_size, void* d_ws, size_t ws_size,
                              hipStream_t stream) {
    const float* grad  = (const float*)d_in[0];
    const float* M     = (const float*)d_in[1];
    const float* state = (const float*)d_in[2];
    const float* L0    = (const float*)d_in[3];
    const float* R0    = (const float*)d_in[4];
    float* out = (float*)d_out;
    char* wsb = (char*)d_ws;

    // region map (<= 73 MB, proven safe):
    u16t* GH  = (u16t*)(wsb);                          // [0,32MB)   GH[n][i][o]
    u16t* AH  = (u16t*)(wsb + ((size_t)32 << 20));     // [32,64MB)  AH[n][i][o]
    u16t* TT  = (u16t*)(wsb + ((size_t)64 << 20));     // [64,72MB)  TT[n][o][p]
    float* CP = (float*)TT;                            // CP aliases TT (dead after k_cols)
    u16t* EH  = TT;                                    // EH aliases TT (dead after k_Abuild)
    float* BS = (float*)(wsb + ((size_t)72 << 20));    // 64KB

    k_prep  <<<1024, 256, 0, stream>>>(grad, L0, out, GH, CP);
    k_cols  <<<64,   256, 0, stream>>>(R0, state, out, BS, CP);
    k_T     <<<256,  256, 0, stream>>>(GH, M, BS, TT);
    k_Abuild<<<512,  256, 0, stream>>>(M, GH, BS, TT, AH);
    k_E     <<<256,  256, 0, stream>>>(AH, EH);
    k_Mnew  <<<512,  256, 0, stream>>>(AH, EH, out);
}

// Round 5
// 165.948 us; speedup vs baseline: 1.7921x; 1.7921x over previous
//
#include <hip/hip_runtime.h>

typedef unsigned short u16t;
typedef unsigned int   u32t;
typedef __bf16 bf16x8 __attribute__((ext_vector_type(8)));
typedef float  f32x4  __attribute__((ext_vector_type(4)));

#define NB   64
#define DIN  1024
#define DOUT 256
#define EPS  1e-4f   // LR*LR
#define KP   68      // LDS row stride in u16: 34 dwords == 2 mod 32 -> conflict-free patterns

#define OUT_STATE (NB*DIN*DOUT)
#define OUT_LL    (OUT_STATE + 1)
#define OUT_RR    (OUT_LL + NB*DIN)

__device__ __forceinline__ u16t f2b(float x) {
    u32t u = __builtin_bit_cast(u32t, x);
    u += 0x7FFFu + ((u >> 16) & 1u);          // RTNE
    return (u16t)(u >> 16);
}
__device__ __forceinline__ float b2f(u16t h) {
    return __builtin_bit_cast(float, ((u32t)h) << 16);
}
// 16B fragment from 8B-aligned LDS (two ds_read_b64)
__device__ __forceinline__ bf16x8 ld_frag(const u16t* p) {
    uint2 lo = *(const uint2*)(p);
    uint2 hi = *(const uint2*)(p + 4);
    union { uint4 u; bf16x8 v; } x;
    x.u = make_uint4(lo.x, lo.y, hi.x, hi.y);
    return x.v;
}
__device__ __forceinline__ void st8(u16t* p, u32t a, u32t b) {
    *(uint2*)(p) = make_uint2(a, b);
}

// ============================================================
// K1: grad row moments -> ll (out), GH = bf16(a*grad), col partials CP.
// No LDS. grid 1024 = (n, 16 i-chunks), block 256. XCD: bid&7 = n&7.
// ============================================================
__global__ __launch_bounds__(256) void k_prep(
    const float* __restrict__ grad, const float* __restrict__ L0,
    float* __restrict__ out, u16t* __restrict__ GH, float* __restrict__ CP)
{
    const int bid = blockIdx.x;
    const int n = (bid & 7) | ((bid >> 7) << 3);
    const int chunk = (bid >> 3) & 15;
    const int tid = threadIdx.x, wave = tid >> 6, lane = tid & 63;
    const int ib = chunk * 64;
    const float* gb = grad + ((size_t)n << 18);
    u16t* GHn = GH + ((size_t)n << 18);

    float4 cacc = {0.f, 0.f, 0.f, 0.f};
    #pragma unroll 4
    for (int r = 0; r < 16; ++r) {
        const int i = ib + wave * 16 + r;
        const float4 v = *(const float4*)(gb + (size_t)i * 256 + lane * 4);
        float s = v.x*v.x + v.y*v.y + v.z*v.z + v.w*v.w;
        cacc.x += v.x*v.x; cacc.y += v.y*v.y; cacc.z += v.z*v.z; cacc.w += v.w*v.w;
        #pragma unroll
        for (int off = 32; off; off >>= 1) s += __shfl_xor(s, off);
        const float l0 = L0[n * DIN + i];
        const float ll = fmaxf(l0, 0.5f * l0 + s * (0.5f / DOUT));
        const float a  = rsqrtf(sqrtf(ll));
        ushort4 g4 = { f2b(v.x*a), f2b(v.y*a), f2b(v.z*a), f2b(v.w*a) };
        *(ushort4*)(GHn + (size_t)i * 256 + lane * 4) = g4;
        if (lane == 0) out[OUT_LL + n * DIN + i] = ll;
    }
    const int slot = chunk * 4 + wave;
    *(float4*)(CP + ((size_t)(n * 64 + slot)) * 256 + lane * 4) = cacc;
}

// ============================================================
// K2: reduce col partials -> rr (out), BS = rr^-1/4 ; copy state
// ============================================================
__global__ __launch_bounds__(256) void k_cols(
    const float* __restrict__ R0, const float* __restrict__ state,
    float* __restrict__ out, float* __restrict__ BS, const float* __restrict__ CP)
{
    const int n = blockIdx.x, o = threadIdx.x;
    const float* cp = CP + (size_t)n * 64 * 256 + o;
    float s = 0.f;
    #pragma unroll 8
    for (int k = 0; k < 64; ++k) s += cp[k * 256];
    const float r0 = R0[n * DOUT + o];
    const float rr = fmaxf(r0, 0.5f * r0 + s * (0.5f / DIN));
    out[OUT_RR + n * DOUT + o] = rr;
    BS[n * DOUT + o] = rsqrtf(sqrtf(rr));
    if (n == 0 && o == 0) out[OUT_STATE] = state[0];
}

// ============================================================
// G1 (k_T): TT[o][p] = b[o] * sum_i GH[i][o] * M[i][p]
// tile 128o x 128p, K=1024. grid 256 = (n, 4 tiles). Both operands
// transpose-staged (GH bf16 cols; M fp32 cols cvt on the fly).
// acc[4][4]=64 VGPR -> min-waves 3 is safe (cap ~170).
// ============================================================
__global__ __launch_bounds__(256, 3) void k_T(
    const u16t* __restrict__ GH, const float* __restrict__ M,
    const float* __restrict__ BS, u16t* __restrict__ TT)
{
    __shared__ u16t sA[128 * KP];   // [o][i]
    __shared__ u16t sB[128 * KP];   // [p][i]
    const int bid = blockIdx.x;
    const int n = (bid & 7) | ((bid >> 5) << 3);
    const int tile = (bid >> 3) & 3;
    const int o0 = (tile & 1) * 128, p0 = (tile >> 1) * 128;
    const int tid = threadIdx.x, lane = tid & 63, w = tid >> 6;
    const int wr = w >> 1, wc = w & 1, t16 = lane & 15, g4 = lane >> 4;
    const u16t* GHn = GH + ((size_t)n << 18);
    const float* Mn = M + ((size_t)n << 18);
    f32x4 acc[4][4] = {};
    for (int ch = 0; ch < 16; ++ch) {
        const int ib = ch * 64;
        __syncthreads();
        // sA: transpose-stage GH rows (o-major). bank = 2*lane -> free
        #pragma unroll
        for (int r = 0; r < 16; ++r) {
            const int il = w * 16 + r;
            const u16t* src = GHn + (size_t)(ib + il) * 256 + o0;
            sA[(size_t)lane * KP + il]        = src[lane];
            sA[(size_t)(lane + 64) * KP + il] = src[lane + 64];
        }
        // sB: transpose-stage fp32 M rows, cvt to bf16
        #pragma unroll
        for (int r = 0; r < 16; ++r) {
            const int il = w * 16 + r;
            const float* src = Mn + (size_t)(ib + il) * 256 + p0;
            sB[(size_t)lane * KP + il]        = f2b(src[lane]);
            sB[(size_t)(lane + 64) * KP + il] = f2b(src[lane + 64]);
        }
        __syncthreads();
        #pragma unroll
        for (int kb = 0; kb < 2; ++kb) {
            const int ko = kb * 32 + g4 * 8;
            bf16x8 fa[4], fb[4];
            #pragma unroll
            for (int fm = 0; fm < 4; ++fm)
                fa[fm] = ld_frag(sA + (wr*64 + fm*16 + t16) * KP + ko);
            #pragma unroll
            for (int fn = 0; fn < 4; ++fn)
                fb[fn] = ld_frag(sB + (wc*64 + fn*16 + t16) * KP + ko);
            #pragma unroll
            for (int fm = 0; fm < 4; ++fm)
                #pragma unroll
                for (int fn = 0; fn < 4; ++fn)
                    acc[fm][fn] = __builtin_amdgcn_mfma_f32_16x16x32_bf16(fa[fm], fb[fn], acc[fm][fn], 0, 0, 0);
        }
    }
    const float* bs = BS + n * DOUT;
    u16t* TTn = TT + ((size_t)n << 16);
    #pragma unroll
    for (int fm = 0; fm < 4; ++fm)
        #pragma unroll
        for (int fn = 0; fn < 4; ++fn) {
            const int p = p0 + wc*64 + fn*16 + t16;
            #pragma unroll
            for (int r = 0; r < 4; ++r) {
                const int o = o0 + wr*64 + fm*16 + g4*4 + r;
                TTn[o * 256 + p] = f2b(acc[fm][fn][r] * bs[o]);
            }
        }
}

// ============================================================
// G2 (k_Abuild): A[i][o] = M + EPS*( sum_p M[i][p]*TT[o][p] - b_o*GH[i][o] )
// tile 128i x 256o (full), K=256. grid 512 = (n, 8 i-tiles). -> AH bf16
// acc[4][8]=128 VGPR accumulator: min-waves MUST stay 2 (3 caps VGPR at
// ~170 and spills acc to scratch -- R3 regression, WRITE_SIZE 3.6x).
// ============================================================
__global__ __launch_bounds__(256, 2) void k_Abuild(
    const float* __restrict__ M, const u16t* __restrict__ GH,
    const float* __restrict__ BS, const u16t* __restrict__ TT,
    u16t* __restrict__ AH)
{
    __shared__ u16t sA[128 * KP];   // [i][p]
    __shared__ u16t sB[256 * KP];   // [o][p]
    const int bid = blockIdx.x;
    const int n = (bid & 7) | ((bid >> 6) << 3);
    const int i0 = ((bid >> 3) & 7) * 128;
    const int tid = threadIdx.x, lane = tid & 63, w = tid >> 6;
    const int wr = w >> 1, wc = w & 1, t16 = lane & 15, g4 = lane >> 4;
    const float* Mn = M + ((size_t)n << 18);
    const u16t* GHn = GH + ((size_t)n << 18);
    const u16t* TTn = TT + ((size_t)n << 16);
    f32x4 acc[4][8] = {};
    for (int ch = 0; ch < 4; ++ch) {
        const int pb = ch * 64;
        __syncthreads();
        // sA: convert fp32 M rows
        #pragma unroll
        for (int q = 0; q < 8; ++q) {
            const int row = (tid >> 4) + 16 * q;
            const int c4  = tid & 15;
            const float4 v = *(const float4*)(Mn + (size_t)(i0 + row) * 256 + pb + c4 * 4);
            ushort4 h = { f2b(v.x), f2b(v.y), f2b(v.z), f2b(v.w) };
            *(ushort4*)(sA + row * KP + c4 * 4) = h;
        }
        // sB: TT rows
        #pragma unroll
        for (int q = 0; q < 8; ++q) {
            const int row = (tid >> 3) + 32 * q;
            const int c8  = (tid & 7) * 8;
            uint4 v = *(const uint4*)(TTn + (size_t)row * 256 + pb + c8);
            st8(sB + row * KP + c8, v.x, v.y);
            st8(sB + row * KP + c8 + 4, v.z, v.w);
        }
        __syncthreads();
        #pragma unroll
        for (int kb = 0; kb < 2; ++kb) {
            const int ko = kb * 32 + g4 * 8;
            bf16x8 fa[4], fb[8];
            #pragma unroll
            for (int fm = 0; fm < 4; ++fm)
                fa[fm] = ld_frag(sA + (wr*64 + fm*16 + t16) * KP + ko);
            #pragma unroll
            for (int fn = 0; fn < 8; ++fn)
                fb[fn] = ld_frag(sB + (wc*128 + fn*16 + t16) * KP + ko);
            #pragma unroll
            for (int fm = 0; fm < 4; ++fm)
                #pragma unroll
                for (int fn = 0; fn < 8; ++fn)
                    acc[fm][fn] = __builtin_amdgcn_mfma_f32_16x16x32_bf16(fa[fm], fb[fn], acc[fm][fn], 0, 0, 0);
        }
    }
    const float* bs = BS + n * DOUT;
    u16t* AHn = AH + ((size_t)n << 18);
    #pragma unroll
    for (int fm = 0; fm < 4; ++fm)
        #pragma unroll
        for (int fn = 0; fn < 8; ++fn) {
            const int o = wc*128 + fn*16 + t16;
            const float bo = bs[o];
            #pragma unroll
            for (int r = 0; r < 4; ++r) {
                const int i = i0 + wr*64 + fm*16 + g4*4 + r;
                const size_t idx = (size_t)i * 256 + o;
                const float Aval = Mn[idx] + EPS * (acc[fm][fn][r] - bo * b2f(GHn[idx]));
                AHn[idx] = f2b(Aval);
            }
        }
}

// ============================================================
// G3 (k_E): EH[p][o] = bf16( 0.5*(A^T A - I) ). tile 128p x 128o, K=1024.
// grid 256 = (n, 4 tiles). Both operands transpose-staged from AH.
// ============================================================
__global__ __launch_bounds__(256, 3) void k_E(
    const u16t* __restrict__ AH, u16t* __restrict__ EH)
{
    __shared__ u16t sA[128 * KP];   // [p][i]
    __shared__ u16t sB[128 * KP];   // [o][i]
    const int bid = blockIdx.x;
    const int n = (bid & 7) | ((bid >> 5) << 3);
    const int tile = (bid >> 3) & 3;
    const int p0 = (tile >> 1) * 128, o0 = (tile & 1) * 128;
    const bool diag = (p0 == o0);
    const int tid = threadIdx.x, lane = tid & 63, w = tid >> 6;
    const int wr = w >> 1, wc = w & 1, t16 = lane & 15, g4 = lane >> 4;
    const u16t* AHn = AH + ((size_t)n << 18);
    f32x4 acc[4][4] = {};
    for (int ch = 0; ch < 16; ++ch) {
        const int ib = ch * 64;
        __syncthreads();
        #pragma unroll
        for (int r = 0; r < 16; ++r) {
            const int il = w * 16 + r;
            const u16t* src = AHn + (size_t)(ib + il) * 256;
            sA[(size_t)lane * KP + il]        = src[p0 + lane];
            sA[(size_t)(lane + 64) * KP + il] = src[p0 + lane + 64];
        }
        if (!diag) {
            #pragma unroll
            for (int r = 0; r < 16; ++r) {
                const int il = w * 16 + r;
                const u16t* src = AHn + (size_t)(ib + il) * 256;
                sB[(size_t)lane * KP + il]        = src[o0 + lane];
                sB[(size_t)(lane + 64) * KP + il] = src[o0 + lane + 64];
            }
        }
        __syncthreads();
        const u16t* sBr = diag ? sA : sB;
        #pragma unroll
        for (int kb = 0; kb < 2; ++kb) {
            const int ko = kb * 32 + g4 * 8;
            bf16x8 fa[4], fb[4];
            #pragma unroll
            for (int fm = 0; fm < 4; ++fm)
                fa[fm] = ld_frag(sA + (wr*64 + fm*16 + t16) * KP + ko);
            #pragma unroll
            for (int fn = 0; fn < 4; ++fn)
                fb[fn] = ld_frag(sBr + (wc*64 + fn*16 + t16) * KP + ko);
            #pragma unroll
            for (int fm = 0; fm < 4; ++fm)
                #pragma unroll
                for (int fn = 0; fn < 4; ++fn)
                    acc[fm][fn] = __builtin_amdgcn_mfma_f32_16x16x32_bf16(fa[fm], fb[fn], acc[fm][fn], 0, 0, 0);
        }
    }
    u16t* EHn = EH + ((size_t)n << 16);
    #pragma unroll
    for (int fm = 0; fm < 4; ++fm)
        #pragma unroll
        for (int fn = 0; fn < 4; ++fn) {
            const int o = o0 + wc*64 + fn*16 + t16;
            #pragma unroll
            for (int r = 0; r < 4; ++r) {
                const int p = p0 + wr*64 + fm*16 + g4*4 + r;
                const float v = 0.5f * acc[fm][fn][r] - (p == o ? 0.5f : 0.f);
                EHn[p * 256 + o] = f2b(v);
            }
        }
}

// ============================================================
// G4 (k_Mnew): Mnew[i][o] = b2f(AH[i][o]) - sum_p AH[i][p]*EH[o][p] (EH sym)
// tile 128i x 256o, K=256. grid 512 = (n, 8 i-tiles).
// acc[4][8]=128 VGPR: min-waves MUST stay 2 (see k_Abuild note).
// ============================================================
__global__ __launch_bounds__(256, 2) void k_Mnew(
    const u16t* __restrict__ AH, const u16t* __restrict__ EH,
    float* __restrict__ out)
{
    __shared__ u16t sA[128 * KP];   // [i][p]
    __shared__ u16t sB[256 * KP];   // [o][p]
    const int bid = blockIdx.x;
    const int n = (bid & 7) | ((bid >> 6) << 3);
    const int i0 = ((bid >> 3) & 7) * 128;
    const int tid = threadIdx.x, lane = tid & 63, w = tid >> 6;
    const int wr = w >> 1, wc = w & 1, t16 = lane & 15, g4 = lane >> 4;
    const u16t* AHn = AH + ((size_t)n << 18);
    const u16t* EHn = EH + ((size_t)n << 16);
    f32x4 acc[4][8] = {};
    for (int ch = 0; ch < 4; ++ch) {
        const int pb = ch * 64;
        __syncthreads();
        #pragma unroll
        for (int q = 0; q < 4; ++q) {
            const int row = (tid >> 3) + 32 * q;
            const int c8  = (tid & 7) * 8;
            uint4 v = *(const uint4*)(AHn + (size_t)(i0 + row) * 256 + pb + c8);
            st8(sA + row * KP + c8, v.x, v.y);
            st8(sA + row * KP + c8 + 4, v.z, v.w);
        }
        #pragma unroll
        for (int q = 0; q < 8; ++q) {
            const int row = (tid >> 3) + 32 * q;
            const int c8  = (tid & 7) * 8;
            uint4 v = *(const uint4*)(EHn + (size_t)row * 256 + pb + c8);
            st8(sB + row * KP + c8, v.x, v.y);
            st8(sB + row * KP + c8 + 4, v.z, v.w);
        }
        __syncthreads();
        #pragma unroll
        for (int kb = 0; kb < 2; ++kb) {
            const int ko = kb * 32 + g4 * 8;
            bf16x8 fa[4], fb[8];
            #pragma unroll
            for (int fm = 0; fm < 4; ++fm)
                fa[fm] = ld_frag(sA + (wr*64 + fm*16 + t16) * KP + ko);
            #pragma unroll
            for (int fn = 0; fn < 8; ++fn)
                fb[fn] = ld_frag(sB + (wc*128 + fn*16 + t16) * KP + ko);
            #pragma unroll
            for (int fm = 0; fm < 4; ++fm)
                #pragma unroll
                for (int fn = 0; fn < 8; ++fn)
                    acc[fm][fn] = __builtin_amdgcn_mfma_f32_16x16x32_bf16(fa[fm], fb[fn], acc[fm][fn], 0, 0, 0);
        }
    }
    float* outn = out + ((size_t)n << 18);
    #pragma unroll
    for (int fm = 0; fm < 4; ++fm)
        #pragma unroll
        for (int fn = 0; fn < 8; ++fn) {
            const int o = wc*128 + fn*16 + t16;
            #pragma unroll
            for (int r = 0; r < 4; ++r) {
                const int i = i0 + wr*64 + fm*16 + g4*4 + r;
                const size_t idx = (size_t)i * 256 + o;
                outn[idx] = b2f(AHn[idx]) - acc[fm][fn][r];
            }
        }
}

extern "C" void kernel_launch(void* const* d_in, const int* in_sizes, int n_in,
                              void* d_out, int out_size, void* d_ws, size_t ws_size,
                              hipStream_t stream) {
    const float* grad  = (const float*)d_in[0];
    const float* M     = (const float*)d_in[1];
    const float* state = (const float*)d_in[2];
    const float* L0    = (const float*)d_in[3];
    const float* R0    = (const float*)d_in[4];
    float* out = (float*)d_out;
    char* wsb = (char*)d_ws;

    // region map (<= 73 MB, proven safe):
    u16t* GH  = (u16t*)(wsb);                          // [0,32MB)   GH[n][i][o]
    u16t* AH  = (u16t*)(wsb + ((size_t)32 << 20));     // [32,64MB)  AH[n][i][o]
    u16t* TT  = (u16t*)(wsb + ((size_t)64 << 20));     // [64,72MB)  TT[n][o][p]
    float* CP = (float*)TT;                            // CP aliases TT (dead after k_cols)
    u16t* EH  = TT;                                    // EH aliases TT (dead after k_Abuild)
    float* BS = (float*)(wsb + ((size_t)72 << 20));    // 64KB

    k_prep  <<<1024, 256, 0, stream>>>(grad, L0, out, GH, CP);
    k_cols  <<<64,   256, 0, stream>>>(R0, state, out, BS, CP);
    k_T     <<<256,  256, 0, stream>>>(GH, M, BS, TT);
    k_Abuild<<<512,  256, 0, stream>>>(M, GH, BS, TT, AH);
    k_E     <<<256,  256, 0, stream>>>(AH, EH);
    k_Mnew  <<<512,  256, 0, stream>>>(AH, EH, out);
}

// Round 6
// 162.096 us; speedup vs baseline: 1.8347x; 1.0238x over previous
//
#include <hip/hip_runtime.h>

typedef unsigned short u16t;
typedef unsigned int   u32t;
typedef __bf16 bf16x8 __attribute__((ext_vector_type(8)));
typedef float  f32x4  __attribute__((ext_vector_type(4)));

#define NB   64
#define DIN  1024
#define DOUT 256
#define EPS  1e-4f   // LR*LR
#define KP   68      // LDS row stride in u16: 34 dwords == 2 mod 32 -> conflict-free

#define OUT_STATE (NB*DIN*DOUT)
#define OUT_LL    (OUT_STATE + 1)
#define OUT_RR    (OUT_LL + NB*DIN)

__device__ __forceinline__ u16t f2b(float x) {
    u32t u = __builtin_bit_cast(u32t, x);
    u += 0x7FFFu + ((u >> 16) & 1u);          // RTNE
    return (u16t)(u >> 16);
}
__device__ __forceinline__ float b2f(u16t h) {
    return __builtin_bit_cast(float, ((u32t)h) << 16);
}
__device__ __forceinline__ bf16x8 ld_frag(const u16t* p) {
    uint2 lo = *(const uint2*)(p);
    uint2 hi = *(const uint2*)(p + 4);
    union { uint4 u; bf16x8 v; } x;
    x.u = make_uint4(lo.x, lo.y, hi.x, hi.y);
    return x.v;
}
__device__ __forceinline__ void st8(u16t* p, u32t a, u32t b) {
    *(uint2*)(p) = make_uint2(a, b);
}

// ============================================================
// K1: grad row moments -> ll (out), GH = bf16(a*grad), col partials CP.
// No LDS. grid 1024 = (n, 16 i-chunks), block 256. XCD: bid&7 = n&7.
// ============================================================
__global__ __launch_bounds__(256) void k_prep(
    const float* __restrict__ grad, const float* __restrict__ L0,
    float* __restrict__ out, u16t* __restrict__ GH, float* __restrict__ CP)
{
    const int bid = blockIdx.x;
    const int n = (bid & 7) | ((bid >> 7) << 3);
    const int chunk = (bid >> 3) & 15;
    const int tid = threadIdx.x, wave = tid >> 6, lane = tid & 63;
    const int ib = chunk * 64;
    const float* gb = grad + ((size_t)n << 18);
    u16t* GHn = GH + ((size_t)n << 18);

    float4 cacc = {0.f, 0.f, 0.f, 0.f};
    #pragma unroll 4
    for (int r = 0; r < 16; ++r) {
        const int i = ib + wave * 16 + r;
        const float4 v = *(const float4*)(gb + (size_t)i * 256 + lane * 4);
        float s = v.x*v.x + v.y*v.y + v.z*v.z + v.w*v.w;
        cacc.x += v.x*v.x; cacc.y += v.y*v.y; cacc.z += v.z*v.z; cacc.w += v.w*v.w;
        #pragma unroll
        for (int off = 32; off; off >>= 1) s += __shfl_xor(s, off);
        const float l0 = L0[n * DIN + i];
        const float ll = fmaxf(l0, 0.5f * l0 + s * (0.5f / DOUT));
        const float a  = rsqrtf(sqrtf(ll));
        ushort4 g4v = { f2b(v.x*a), f2b(v.y*a), f2b(v.z*a), f2b(v.w*a) };
        *(ushort4*)(GHn + (size_t)i * 256 + lane * 4) = g4v;
        if (lane == 0) out[OUT_LL + n * DIN + i] = ll;
    }
    const int slot = chunk * 4 + wave;
    *(float4*)(CP + ((size_t)(n * 64 + slot)) * 256 + lane * 4) = cacc;
}

// ============================================================
// K2: reduce col partials -> rr (out), BS = rr^-1/4 ; copy state
// ============================================================
__global__ __launch_bounds__(256) void k_cols(
    const float* __restrict__ R0, const float* __restrict__ state,
    float* __restrict__ out, float* __restrict__ BS, const float* __restrict__ CP)
{
    const int n = blockIdx.x, o = threadIdx.x;
    const float* cp = CP + (size_t)n * 64 * 256 + o;
    float s = 0.f;
    #pragma unroll 8
    for (int k = 0; k < 64; ++k) s += cp[k * 256];
    const float r0 = R0[n * DOUT + o];
    const float rr = fmaxf(r0, 0.5f * r0 + s * (0.5f / DIN));
    out[OUT_RR + n * DOUT + o] = rr;
    BS[n * DOUT + o] = rsqrtf(sqrtf(rr));
    if (n == 0 && o == 0) out[OUT_STATE] = state[0];
}

// ============================================================
// G1 (k_T): TT[o][p] = b[o] * sum_i GH[i][o] * M[i][p]
// 512 thr (8 waves, 2x4), tile 128o x 128p, K=1024, reg-prefetch dbuf.
// grid 256 = (n, 4 tiles).
// ============================================================
__global__ __launch_bounds__(512, 2) void k_T(
    const u16t* __restrict__ GH, const float* __restrict__ M,
    const float* __restrict__ BS, u16t* __restrict__ TT)
{
    __shared__ u16t sA[128 * KP];   // [o][i]
    __shared__ u16t sB[128 * KP];   // [p][i]
    const int bid = blockIdx.x;
    const int n = (bid & 7) | ((bid >> 5) << 3);
    const int tile = (bid >> 3) & 3;
    const int o0 = (tile & 1) * 128, p0 = (tile >> 1) * 128;
    const int t = threadIdx.x, lane = t & 63, w = t >> 6;
    const int wr = w >> 2, wc = w & 3, t16 = lane & 15, g4 = lane >> 4;
    const int cA = t & 127, ig = t >> 7;       // staging: col + i-group
    const u16t* GHn = GH + ((size_t)n << 18);
    const float* Mn = M + ((size_t)n << 18);
    u16t rA[16]; float rB[16];
    f32x4 acc[4][2] = {};

#define T_LOAD(ch) { const int ib_ = (ch) * 64; \
    _Pragma("unroll") for (int r = 0; r < 16; ++r) { \
        const int il = ig * 16 + r; \
        rA[r] = GHn[(size_t)(ib_ + il) * 256 + o0 + cA]; \
        rB[r] = Mn[(size_t)(ib_ + il) * 256 + p0 + cA]; } }

    T_LOAD(0);
    for (int ch = 0; ch < 16; ++ch) {
        __syncthreads();
        #pragma unroll
        for (int r = 0; r < 16; ++r) {
            const int il = ig * 16 + r;
            sA[cA * KP + il] = rA[r];
            sB[cA * KP + il] = f2b(rB[r]);
        }
        __syncthreads();
        if (ch < 15) T_LOAD(ch + 1);     // overlaps MFMA below
        #pragma unroll
        for (int kb = 0; kb < 2; ++kb) {
            const int ko = kb * 32 + g4 * 8;
            bf16x8 fa[4], fb[2];
            #pragma unroll
            for (int fm = 0; fm < 4; ++fm)
                fa[fm] = ld_frag(sA + (wr*64 + fm*16 + t16) * KP + ko);
            #pragma unroll
            for (int fn = 0; fn < 2; ++fn)
                fb[fn] = ld_frag(sB + (wc*32 + fn*16 + t16) * KP + ko);
            #pragma unroll
            for (int fm = 0; fm < 4; ++fm)
                #pragma unroll
                for (int fn = 0; fn < 2; ++fn)
                    acc[fm][fn] = __builtin_amdgcn_mfma_f32_16x16x32_bf16(fa[fm], fb[fn], acc[fm][fn], 0, 0, 0);
        }
    }
    const float* bs = BS + n * DOUT;
    u16t* TTn = TT + ((size_t)n << 16);
    #pragma unroll
    for (int fm = 0; fm < 4; ++fm)
        #pragma unroll
        for (int fn = 0; fn < 2; ++fn) {
            const int p = p0 + wc*32 + fn*16 + t16;
            #pragma unroll
            for (int r = 0; r < 4; ++r) {
                const int o = o0 + wr*64 + fm*16 + g4*4 + r;
                TTn[o * 256 + p] = f2b(acc[fm][fn][r] * bs[o]);
            }
        }
}

// ============================================================
// G2 (k_Abuild): A[i][o] = M + EPS*( sum_p M[i][p]*TT[o][p] - b_o*GH[i][o] )
// 512 thr, tile 128i x 256o, K=256, reg-prefetch dbuf. grid 512. -> AH bf16
// ============================================================
__global__ __launch_bounds__(512, 2) void k_Abuild(
    const float* __restrict__ M, const u16t* __restrict__ GH,
    const float* __restrict__ BS, const u16t* __restrict__ TT,
    u16t* __restrict__ AH)
{
    __shared__ u16t sA[128 * KP];   // [i][p]
    __shared__ u16t sB[256 * KP];   // [o][p]
    const int bid = blockIdx.x;
    const int n = (bid & 7) | ((bid >> 6) << 3);
    const int i0 = ((bid >> 3) & 7) * 128;
    const int t = threadIdx.x, lane = t & 63, w = t >> 6;
    const int wr = w >> 2, wc = w & 3, t16 = lane & 15, g4 = lane >> 4;
    const float* Mn = M + ((size_t)n << 18);
    const u16t* GHn = GH + ((size_t)n << 18);
    const u16t* TTn = TT + ((size_t)n << 16);
    float4 rMa[4];
    uint4  rTb[4];
    f32x4 acc[4][4] = {};

#define AB_LOAD(ch) { const int pb_ = (ch) * 64; \
    _Pragma("unroll") for (int j = 0; j < 2; ++j) { \
        const int s = j * 512 + t, row = s >> 3, c8 = (s & 7) * 8; \
        rMa[2*j+0] = *(const float4*)(Mn + (size_t)(i0 + row) * 256 + pb_ + c8); \
        rMa[2*j+1] = *(const float4*)(Mn + (size_t)(i0 + row) * 256 + pb_ + c8 + 4); } \
    _Pragma("unroll") for (int j = 0; j < 4; ++j) { \
        const int s = j * 512 + t, row = s >> 3, c8 = (s & 7) * 8; \
        rTb[j] = *(const uint4*)(TTn + (size_t)row * 256 + pb_ + c8); } }

    AB_LOAD(0);
    for (int ch = 0; ch < 4; ++ch) {
        __syncthreads();
        #pragma unroll
        for (int j = 0; j < 2; ++j) {
            const int s = j * 512 + t, row = s >> 3, c8 = (s & 7) * 8;
            const float4 v0 = rMa[2*j+0], v1 = rMa[2*j+1];
            ushort4 h0 = { f2b(v0.x), f2b(v0.y), f2b(v0.z), f2b(v0.w) };
            ushort4 h1 = { f2b(v1.x), f2b(v1.y), f2b(v1.z), f2b(v1.w) };
            *(ushort4*)(sA + row * KP + c8)     = h0;
            *(ushort4*)(sA + row * KP + c8 + 4) = h1;
        }
        #pragma unroll
        for (int j = 0; j < 4; ++j) {
            const int s = j * 512 + t, row = s >> 3, c8 = (s & 7) * 8;
            st8(sB + row * KP + c8,     rTb[j].x, rTb[j].y);
            st8(sB + row * KP + c8 + 4, rTb[j].z, rTb[j].w);
        }
        __syncthreads();
        if (ch < 3) AB_LOAD(ch + 1);
        #pragma unroll
        for (int kb = 0; kb < 2; ++kb) {
            const int ko = kb * 32 + g4 * 8;
            bf16x8 fa[4], fb[4];
            #pragma unroll
            for (int fm = 0; fm < 4; ++fm)
                fa[fm] = ld_frag(sA + (wr*64 + fm*16 + t16) * KP + ko);
            #pragma unroll
            for (int fn = 0; fn < 4; ++fn)
                fb[fn] = ld_frag(sB + (wc*64 + fn*16 + t16) * KP + ko);
            #pragma unroll
            for (int fm = 0; fm < 4; ++fm)
                #pragma unroll
                for (int fn = 0; fn < 4; ++fn)
                    acc[fm][fn] = __builtin_amdgcn_mfma_f32_16x16x32_bf16(fa[fm], fb[fn], acc[fm][fn], 0, 0, 0);
        }
    }
    const float* bs = BS + n * DOUT;
    u16t* AHn = AH + ((size_t)n << 18);
    #pragma unroll
    for (int fm = 0; fm < 4; ++fm)
        #pragma unroll
        for (int fn = 0; fn < 4; ++fn) {
            const int o = wc*64 + fn*16 + t16;
            const float bo = bs[o];
            #pragma unroll
            for (int r = 0; r < 4; ++r) {
                const int i = i0 + wr*64 + fm*16 + g4*4 + r;
                const size_t idx = (size_t)i * 256 + o;
                const float Aval = Mn[idx] + EPS * (acc[fm][fn][r] - bo * b2f(GHn[idx]));
                AHn[idx] = f2b(Aval);
            }
        }
}

// ============================================================
// G3 (k_E): EH[p][o] = bf16( 0.5*(A^T A - I) ). 512 thr, tile 128x128,
// K=1024, reg-prefetch dbuf. grid 256 = (n, 4 tiles).
// ============================================================
__global__ __launch_bounds__(512, 2) void k_E(
    const u16t* __restrict__ AH, u16t* __restrict__ EH)
{
    __shared__ u16t sA[128 * KP];   // [p][i]
    __shared__ u16t sB[128 * KP];   // [o][i]
    const int bid = blockIdx.x;
    const int n = (bid & 7) | ((bid >> 5) << 3);
    const int tile = (bid >> 3) & 3;
    const int p0 = (tile >> 1) * 128, o0 = (tile & 1) * 128;
    const bool diag = (p0 == o0);
    const int t = threadIdx.x, lane = t & 63, w = t >> 6;
    const int wr = w >> 2, wc = w & 3, t16 = lane & 15, g4 = lane >> 4;
    const int cA = t & 127, ig = t >> 7;
    const u16t* AHn = AH + ((size_t)n << 18);
    u16t rA[16], rB[16];
    f32x4 acc[4][2] = {};

#define E_LOAD(ch) { const int ib_ = (ch) * 64; \
    _Pragma("unroll") for (int r = 0; r < 16; ++r) { \
        const int il = ig * 16 + r; \
        const u16t* src = AHn + (size_t)(ib_ + il) * 256; \
        rA[r] = src[p0 + cA]; \
        if (!diag) rB[r] = src[o0 + cA]; } }

    E_LOAD(0);
    for (int ch = 0; ch < 16; ++ch) {
        __syncthreads();
        #pragma unroll
        for (int r = 0; r < 16; ++r) {
            const int il = ig * 16 + r;
            sA[cA * KP + il] = rA[r];
            if (!diag) sB[cA * KP + il] = rB[r];
        }
        __syncthreads();
        if (ch < 15) E_LOAD(ch + 1);
        const u16t* sBr = diag ? sA : sB;
        #pragma unroll
        for (int kb = 0; kb < 2; ++kb) {
            const int ko = kb * 32 + g4 * 8;
            bf16x8 fa[4], fb[2];
            #pragma unroll
            for (int fm = 0; fm < 4; ++fm)
                fa[fm] = ld_frag(sA + (wr*64 + fm*16 + t16) * KP + ko);
            #pragma unroll
            for (int fn = 0; fn < 2; ++fn)
                fb[fn] = ld_frag(sBr + (wc*32 + fn*16 + t16) * KP + ko);
            #pragma unroll
            for (int fm = 0; fm < 4; ++fm)
                #pragma unroll
                for (int fn = 0; fn < 2; ++fn)
                    acc[fm][fn] = __builtin_amdgcn_mfma_f32_16x16x32_bf16(fa[fm], fb[fn], acc[fm][fn], 0, 0, 0);
        }
    }
    u16t* EHn = EH + ((size_t)n << 16);
    #pragma unroll
    for (int fm = 0; fm < 4; ++fm)
        #pragma unroll
        for (int fn = 0; fn < 2; ++fn) {
            const int o = o0 + wc*32 + fn*16 + t16;
            #pragma unroll
            for (int r = 0; r < 4; ++r) {
                const int p = p0 + wr*64 + fm*16 + g4*4 + r;
                const float v = 0.5f * acc[fm][fn][r] - (p == o ? 0.5f : 0.f);
                EHn[p * 256 + o] = f2b(v);
            }
        }
}

// ============================================================
// G4 (k_Mnew): Mnew[i][o] = b2f(AH[i][o]) - sum_p AH[i][p]*EH[o][p] (EH sym)
// 512 thr, tile 128i x 256o, K=256, reg-prefetch dbuf. grid 512.
// ============================================================
__global__ __launch_bounds__(512, 2) void k_Mnew(
    const u16t* __restrict__ AH, const u16t* __restrict__ EH,
    float* __restrict__ out)
{
    __shared__ u16t sA[128 * KP];   // [i][p]
    __shared__ u16t sB[256 * KP];   // [o][p]
    const int bid = blockIdx.x;
    const int n = (bid & 7) | ((bid >> 6) << 3);
    const int i0 = ((bid >> 3) & 7) * 128;
    const int t = threadIdx.x, lane = t & 63, w = t >> 6;
    const int wr = w >> 2, wc = w & 3, t16 = lane & 15, g4 = lane >> 4;
    const u16t* AHn = AH + ((size_t)n << 18);
    const u16t* EHn = EH + ((size_t)n << 16);
    uint4 rAa[2], rEb[4];
    f32x4 acc[4][4] = {};

#define MN_LOAD(ch) { const int pb_ = (ch) * 64; \
    _Pragma("unroll") for (int j = 0; j < 2; ++j) { \
        const int s = j * 512 + t, row = s >> 3, c8 = (s & 7) * 8; \
        rAa[j] = *(const uint4*)(AHn + (size_t)(i0 + row) * 256 + pb_ + c8); } \
    _Pragma("unroll") for (int j = 0; j < 4; ++j) { \
        const int s = j * 512 + t, row = s >> 3, c8 = (s & 7) * 8; \
        rEb[j] = *(const uint4*)(EHn + (size_t)row * 256 + pb_ + c8); } }

    MN_LOAD(0);
    for (int ch = 0; ch < 4; ++ch) {
        __syncthreads();
        #pragma unroll
        for (int j = 0; j < 2; ++j) {
            const int s = j * 512 + t, row = s >> 3, c8 = (s & 7) * 8;
            st8(sA + row * KP + c8,     rAa[j].x, rAa[j].y);
            st8(sA + row * KP + c8 + 4, rAa[j].z, rAa[j].w);
        }
        #pragma unroll
        for (int j = 0; j < 4; ++j) {
            const int s = j * 512 + t, row = s >> 3, c8 = (s & 7) * 8;
            st8(sB + row * KP + c8,     rEb[j].x, rEb[j].y);
            st8(sB + row * KP + c8 + 4, rEb[j].z, rEb[j].w);
        }
        __syncthreads();
        if (ch < 3) MN_LOAD(ch + 1);
        #pragma unroll
        for (int kb = 0; kb < 2; ++kb) {
            const int ko = kb * 32 + g4 * 8;
            bf16x8 fa[4], fb[4];
            #pragma unroll
            for (int fm = 0; fm < 4; ++fm)
                fa[fm] = ld_frag(sA + (wr*64 + fm*16 + t16) * KP + ko);
            #pragma unroll
            for (int fn = 0; fn < 4; ++fn)
                fb[fn] = ld_frag(sB + (wc*64 + fn*16 + t16) * KP + ko);
            #pragma unroll
            for (int fm = 0; fm < 4; ++fm)
                #pragma unroll
                for (int fn = 0; fn < 4; ++fn)
                    acc[fm][fn] = __builtin_amdgcn_mfma_f32_16x16x32_bf16(fa[fm], fb[fn], acc[fm][fn], 0, 0, 0);
        }
    }
    float* outn = out + ((size_t)n << 18);
    #pragma unroll
    for (int fm = 0; fm < 4; ++fm)
        #pragma unroll
        for (int fn = 0; fn < 4; ++fn) {
            const int o = wc*64 + fn*16 + t16;
            #pragma unroll
            for (int r = 0; r < 4; ++r) {
                const int i = i0 + wr*64 + fm*16 + g4*4 + r;
                const size_t idx = (size_t)i * 256 + o;
                outn[idx] = b2f(AHn[idx]) - acc[fm][fn][r];
            }
        }
}

extern "C" void kernel_launch(void* const* d_in, const int* in_sizes, int n_in,
                              void* d_out, int out_size, void* d_ws, size_t ws_size,
                              hipStream_t stream) {
    const float* grad  = (const float*)d_in[0];
    const float* M     = (const float*)d_in[1];
    const float* state = (const float*)d_in[2];
    const float* L0    = (const float*)d_in[3];
    const float* R0    = (const float*)d_in[4];
    float* out = (float*)d_out;
    char* wsb = (char*)d_ws;

    // region map (<= 73 MB, proven safe):
    u16t* GH  = (u16t*)(wsb);                          // [0,32MB)   GH[n][i][o]
    u16t* AH  = (u16t*)(wsb + ((size_t)32 << 20));     // [32,64MB)  AH[n][i][o]
    u16t* TT  = (u16t*)(wsb + ((size_t)64 << 20));     // [64,72MB)  TT[n][o][p]
    float* CP = (float*)TT;                            // CP aliases TT (dead after k_cols)
    u16t* EH  = TT;                                    // EH aliases TT (dead after k_Abuild)
    float* BS = (float*)(wsb + ((size_t)72 << 20));    // 64KB

    k_prep  <<<1024, 256, 0, stream>>>(grad, L0, out, GH, CP);
    k_cols  <<<64,   256, 0, stream>>>(R0, state, out, BS, CP);
    k_T     <<<256,  512, 0, stream>>>(GH, M, BS, TT);
    k_Abuild<<<512,  512, 0, stream>>>(M, GH, BS, TT, AH);
    k_E     <<<256,  512, 0, stream>>>(AH, EH);
    k_Mnew  <<<512,  512, 0, stream>>>(AH, EH, out);
}